// Round 2
// baseline (355.514 us; speedup 1.0000x reference)
//
#include <hip/hip_runtime.h>

#define NS 4096
#define NC 32
#define NA 500
#define NV 125        // NA/4 float4 columns per sample-channel row
#define MIN_VALUE 0.01f

// One wave (64 lanes) per sample. Lane t owns float4 column t, and lanes
// t<61 additionally own column 64+t (64+61 = 125 = NV). Reduction is a pure
// in-wave shuffle butterfly: no LDS, no __syncthreads.
__global__ __launch_bounds__(64) void gamma_obo_kernel(
    const float* __restrict__ x,   // (NS, NC, NA)
    const float* __restrict__ W,   // (1, NC)
    const float* __restrict__ b,   // (1,)
    float* __restrict__ out)       // (NS,)
{
    const int s = blockIdx.x;
    const int t = threadIdx.x;     // 0..63

    float w[NC];
#pragma unroll
    for (int c = 0; c < NC; ++c) w[c] = W[c];
    const float bias = b[0];

    const float4* __restrict__ xrow =
        (const float4*)(x + (size_t)s * (NC * NA));

    float4 acc0 = make_float4(bias, bias, bias, bias);
#pragma unroll
    for (int c = 0; c < NC; ++c) {
        float4 v = xrow[c * NV + t];
        acc0.x = fmaf(w[c], v.x, acc0.x);
        acc0.y = fmaf(w[c], v.y, acc0.y);
        acc0.z = fmaf(w[c], v.z, acc0.z);
        acc0.w = fmaf(w[c], v.w, acc0.w);
    }
    float partial = fabsf(acc0.x) + fabsf(acc0.y) + fabsf(acc0.z) + fabsf(acc0.w);

    if (t < NV - 64) {             // lanes 0..60 take columns 64..124
        float4 acc1 = make_float4(bias, bias, bias, bias);
#pragma unroll
        for (int c = 0; c < NC; ++c) {
            float4 v = xrow[c * NV + 64 + t];
            acc1.x = fmaf(w[c], v.x, acc1.x);
            acc1.y = fmaf(w[c], v.y, acc1.y);
            acc1.z = fmaf(w[c], v.z, acc1.z);
            acc1.w = fmaf(w[c], v.w, acc1.w);
        }
        partial += fabsf(acc1.x) + fabsf(acc1.y) + fabsf(acc1.z) + fabsf(acc1.w);
    }

    // 64-lane butterfly reduction, no LDS.
#pragma unroll
    for (int mask = 32; mask > 0; mask >>= 1)
        partial += __shfl_xor(partial, mask, 64);

    if (t == 0)
        out[s] = partial * (1.0f / (float)NA) + MIN_VALUE;
}

extern "C" void kernel_launch(void* const* d_in, const int* in_sizes, int n_in,
                              void* d_out, int out_size, void* d_ws, size_t ws_size,
                              hipStream_t stream) {
    const float* x = (const float*)d_in[0];
    const float* W = (const float*)d_in[1];
    const float* b = (const float*)d_in[2];
    float* out = (float*)d_out;
    gamma_obo_kernel<<<NS, 64, 0, stream>>>(x, W, b, out);
}